// Round 1
// baseline (580.134 us; speedup 1.0000x reference)
//
#include <hip/hip_runtime.h>

#define MEM_SIZE 1000000
#define DIM 128
#define BS 256
#define K 1024
#define NSC (K + 1)   // 1025 scores per (modality, batch)

constexpr float INV_TEMP = 1.0f / 0.07f;
constexpr float MOM = 0.5f;   // MOM_V == MOM_A == 0.5

__device__ __forceinline__ float wave_reduce_sum(float v) {
    #pragma unroll
    for (int off = 32; off > 0; off >>= 1)
        v += __shfl_xor(v, off, 64);
    return v;
}

// One wave (64 lanes) per embedding row; lane handles a float2.
// Blocks 0..255 -> video, 256..511 -> audio.
// ws layout: [0, BS*DIM) = vnorm, [BS*DIM, 2*BS*DIM) = anorm
__global__ void norm_kernel(const float* __restrict__ video,
                            const float* __restrict__ audio,
                            float* __restrict__ ws_norm) {
    const int blk = blockIdx.x;
    const int lane = threadIdx.x;
    const int b = blk & (BS - 1);
    const float* src = (blk < BS) ? video : audio;
    float* dst = ws_norm + ((blk < BS) ? 0 : BS * DIM);
    const float2 val = reinterpret_cast<const float2*>(src + b * DIM)[lane];
    float ss = val.x * val.x + val.y * val.y;
    ss = wave_reduce_sum(ss);
    const float inv = 1.0f / fmaxf(sqrtf(ss), 1e-12f);
    reinterpret_cast<float2*>(dst + b * DIM)[lane] =
        make_float2(val.x * inv, val.y * inv);
}

// One wave per score element. scores flat layout [2][BS][NSC].
// m=0: view2_mem rows dotted with vnorm; m=1: view1_mem rows dotted with anorm.
__global__ void scores_kernel(const int* __restrict__ y,
                              const int* __restrict__ neg_idx,
                              const float* __restrict__ view1,
                              const float* __restrict__ view2,
                              const float* __restrict__ ws_norm,
                              float* __restrict__ scores) {
    const int gtid = blockIdx.x * blockDim.x + threadIdx.x;
    const int w = gtid >> 6;           // global wave id == score id
    const int lane = threadIdx.x & 63;
    const int j = w % NSC;
    const int bm = w / NSC;
    const int b = bm & (BS - 1);
    const int m = bm >> 8;
    const int yb = y[b];
    int row;
    if (j == 0) {
        row = yb;
    } else {
        const int ni = neg_idx[b * K + (j - 1)];
        row = ni + (ni >= yb ? 1 : 0);
    }
    const float* mem = (m == 0) ? view2 : view1;
    const float* vec = ws_norm + ((m == 0) ? 0 : BS * DIM) + b * DIM;
    const float2 xm =
        reinterpret_cast<const float2*>(mem + (long long)row * DIM)[lane];
    const float2 xv = reinterpret_cast<const float2*>(vec)[lane];
    float s = xm.x * xv.x + xm.y * xv.y;
    s = wave_reduce_sum(s);
    if (lane == 0) scores[w] = s * INV_TEMP;
}

// Grid-stride float4 copy of both banks into the output regions.
__global__ void copy_kernel(const float4* __restrict__ src1,
                            const float4* __restrict__ src2,
                            float4* __restrict__ dst1,
                            float4* __restrict__ dst2) {
    const long long n4 = (long long)MEM_SIZE * DIM / 4;   // 32,000,000
    long long i = blockIdx.x * (long long)blockDim.x + threadIdx.x;
    const long long stride = (long long)gridDim.x * blockDim.x;
    for (; i < n4; i += stride) {
        dst1[i] = src1[i];
        dst2[i] = src2[i];
    }
}

// After the copy: overwrite the 256 updated rows per bank.
// Blocks 0..255 -> bank1 (video), 256..511 -> bank2 (audio).
// Duplicate y: numpy "last wins" -> skip b if a later b' has the same index.
__global__ void scatter_kernel(const int* __restrict__ y,
                               const float* __restrict__ view1,
                               const float* __restrict__ view2,
                               const float* __restrict__ ws_norm,
                               float* __restrict__ out1,
                               float* __restrict__ out2) {
    const int blk = blockIdx.x;
    const int lane = threadIdx.x;
    const int bank = blk >> 8;
    const int b = blk & (BS - 1);
    const int row = y[b];
    for (int b2 = b + 1; b2 < BS; ++b2)
        if (y[b2] == row) return;   // a later write supersedes this one
    const float* mem = (bank == 0) ? view1 : view2;
    const float* vec = ws_norm + bank * BS * DIM + b * DIM;
    const float2 xp =
        reinterpret_cast<const float2*>(mem + (long long)row * DIM)[lane];
    const float2 xv = reinterpret_cast<const float2*>(vec)[lane];
    float2 nv = make_float2(MOM * xp.x + (1.0f - MOM) * xv.x,
                            MOM * xp.y + (1.0f - MOM) * xv.y);
    float ss = wave_reduce_sum(nv.x * nv.x + nv.y * nv.y);
    const float inv = 1.0f / fmaxf(sqrtf(ss), 1e-12f);
    float* out = (bank == 0) ? out1 : out2;
    reinterpret_cast<float2*>(out + (long long)row * DIM)[lane] =
        make_float2(nv.x * inv, nv.y * inv);
}

extern "C" void kernel_launch(void* const* d_in, const int* in_sizes, int n_in,
                              void* d_out, int out_size, void* d_ws, size_t ws_size,
                              hipStream_t stream) {
    const float* video = (const float*)d_in[0];
    const float* audio = (const float*)d_in[1];
    const int* y       = (const int*)d_in[2];
    const int* neg     = (const int*)d_in[3];
    const float* v1    = (const float*)d_in[4];
    const float* v2    = (const float*)d_in[5];

    float* out    = (float*)d_out;
    float* scores = out;                                   // [2,256,1025]
    float* out1   = out + 2 * BS * NSC;                    // +524800
    float* out2   = out1 + (long long)MEM_SIZE * DIM;      // +128e6
    float* wsn    = (float*)d_ws;                          // 2*BS*DIM floats

    norm_kernel<<<2 * BS, 64, 0, stream>>>(video, audio, wsn);

    const int n_waves = 2 * BS * NSC;                      // 524800 scores
    const int blocks = (n_waves * 64) / 256;               // 131200
    scores_kernel<<<blocks, 256, 0, stream>>>(y, neg, v1, v2, wsn, scores);

    copy_kernel<<<2048, 256, 0, stream>>>((const float4*)v1, (const float4*)v2,
                                          (float4*)out1, (float4*)out2);

    scatter_kernel<<<2 * BS, 64, 0, stream>>>(y, v1, v2, wsn, out1, out2);
}

// Round 3
// 428.134 us; speedup vs baseline: 1.3550x; 1.3550x over previous
//
#include <hip/hip_runtime.h>

#define MEM_SIZE 1000000
#define DIM 128
#define BS 256
#define K 1024
#define NSC (K + 1)   // 1025 scores per (modality, batch)

constexpr float INV_TEMP = 1.0f / 0.07f;
constexpr float MOM = 0.5f;

// 2048 total blocks; every 4th block is a score block (512), rest copy (1536).
#define TOTAL_BLOCKS 2048
#define COPY_BLOCKS  1536

typedef float fx4 __attribute__((ext_vector_type(4)));

__device__ __forceinline__ float wave_reduce_sum(float v) {
    #pragma unroll
    for (int off = 32; off > 0; off >>= 1)
        v += __shfl_xor(v, off, 64);
    return v;
}

// Fused kernel:
//  - score blocks ((bid&3)==0): one (m,b) row per block, 4 waves split the 1025
//    scores. Query vec normalized in-registers per wave. 2-way unrolled gathers.
//  - copy blocks: grid-stride nontemporal fx4 copy of both banks.
__global__ __launch_bounds__(256) void fused_kernel(
    const float* __restrict__ video, const float* __restrict__ audio,
    const int* __restrict__ y, const int* __restrict__ neg,
    const float* __restrict__ view1, const float* __restrict__ view2,
    float* __restrict__ scores,
    fx4* __restrict__ out1, fx4* __restrict__ out2) {
    const int bid = blockIdx.x;
    const int tid = threadIdx.x;

    if ((bid & 3) == 0) {
        // ---- scores ----
        const int bm = bid >> 2;              // 0..511
        const int m = bm >> 8;                // 0: view2·v, 1: view1·a
        const int b = bm & (BS - 1);
        const int lane = tid & 63;
        const int wv = tid >> 6;              // wave 0..3
        const int yb = y[b];

        const float* emb = (m == 0) ? video : audio;
        const float2 e = reinterpret_cast<const float2*>(emb + b * DIM)[lane];
        const float ss = wave_reduce_sum(e.x * e.x + e.y * e.y);
        const float inv = 1.0f / fmaxf(sqrtf(ss), 1e-12f);
        const float vx = e.x * inv, vy = e.y * inv;

        const float2* mem2 =
            reinterpret_cast<const float2*>((m == 0) ? view2 : view1);
        float* srow = scores + (size_t)bm * NSC;
        const int* nb = neg + b * K;

        const int chunk = (NSC + 3) / 4;      // 257
        const int j0 = wv * chunk;
        const int j1 = min(NSC, j0 + chunk);

        int j = j0;
        for (; j + 1 < j1; j += 2) {
            int r0;
            if (j == 0) r0 = yb;
            else { const int ni = nb[j - 1]; r0 = ni + (ni >= yb ? 1 : 0); }
            const int ni1 = nb[j];            // j+1 >= 1 always
            const int r1 = ni1 + (ni1 >= yb ? 1 : 0);
            const float2 x0 = mem2[(size_t)r0 * 64 + lane];
            const float2 x1 = mem2[(size_t)r1 * 64 + lane];
            const float s0 = wave_reduce_sum(x0.x * vx + x0.y * vy);
            const float s1 = wave_reduce_sum(x1.x * vx + x1.y * vy);
            if (lane == 0) {
                srow[j] = s0 * INV_TEMP;
                srow[j + 1] = s1 * INV_TEMP;
            }
        }
        if (j < j1) {
            int r0;
            if (j == 0) r0 = yb;
            else { const int ni = nb[j - 1]; r0 = ni + (ni >= yb ? 1 : 0); }
            const float2 x0 = mem2[(size_t)r0 * 64 + lane];
            const float s0 = wave_reduce_sum(x0.x * vx + x0.y * vy);
            if (lane == 0) srow[j] = s0 * INV_TEMP;
        }
    } else {
        // ---- bank copy ----
        const long long n4 = (long long)MEM_SIZE * DIM / 4;   // 32M fx4
        const int cb = bid - (bid >> 2) - 1;  // 0..1535 among copy blocks
        const fx4* s1 = reinterpret_cast<const fx4*>(view1);
        const fx4* s2 = reinterpret_cast<const fx4*>(view2);
        long long i = (long long)cb * blockDim.x + tid;
        const long long stride = (long long)COPY_BLOCKS * blockDim.x;
        for (; i < n4; i += stride) {
            const fx4 a = __builtin_nontemporal_load(&s1[i]);
            const fx4 c = __builtin_nontemporal_load(&s2[i]);
            __builtin_nontemporal_store(a, &out1[i]);
            __builtin_nontemporal_store(c, &out2[i]);
        }
    }
}

// Overwrite the 256 momentum-updated rows per bank (after the copy).
// Blocks 0..255 -> bank1 (video), 256..511 -> bank2 (audio).
// Duplicate y: numpy "last wins" -> skip b if a later b' has the same index.
__global__ void scatter_kernel(const float* __restrict__ video,
                               const float* __restrict__ audio,
                               const int* __restrict__ y,
                               const float* __restrict__ view1,
                               const float* __restrict__ view2,
                               float* __restrict__ out1,
                               float* __restrict__ out2) {
    const int blk = blockIdx.x;
    const int lane = threadIdx.x;
    const int bank = blk >> 8;
    const int b = blk & (BS - 1);
    const int row = y[b];
    for (int b2 = b + 1; b2 < BS; ++b2)
        if (y[b2] == row) return;   // a later write supersedes this one

    const float* emb = (bank == 0) ? video : audio;
    const float2 e = reinterpret_cast<const float2*>(emb + b * DIM)[lane];
    const float ss = wave_reduce_sum(e.x * e.x + e.y * e.y);
    const float inv = 1.0f / fmaxf(sqrtf(ss), 1e-12f);
    const float vx = e.x * inv, vy = e.y * inv;

    const float* mem = (bank == 0) ? view1 : view2;
    const float2 xp =
        reinterpret_cast<const float2*>(mem + (size_t)row * DIM)[lane];
    float2 nv = make_float2(MOM * xp.x + (1.0f - MOM) * vx,
                            MOM * xp.y + (1.0f - MOM) * vy);
    const float ss2 = wave_reduce_sum(nv.x * nv.x + nv.y * nv.y);
    const float inv2 = 1.0f / fmaxf(sqrtf(ss2), 1e-12f);
    float* out = (bank == 0) ? out1 : out2;
    reinterpret_cast<float2*>(out + (size_t)row * DIM)[lane] =
        make_float2(nv.x * inv2, nv.y * inv2);
}

extern "C" void kernel_launch(void* const* d_in, const int* in_sizes, int n_in,
                              void* d_out, int out_size, void* d_ws, size_t ws_size,
                              hipStream_t stream) {
    const float* video = (const float*)d_in[0];
    const float* audio = (const float*)d_in[1];
    const int* y       = (const int*)d_in[2];
    const int* neg     = (const int*)d_in[3];
    const float* v1    = (const float*)d_in[4];
    const float* v2    = (const float*)d_in[5];

    float* out    = (float*)d_out;
    float* scores = out;                                   // [2,256,1025]
    float* out1   = out + 2 * BS * NSC;                    // +524800
    float* out2   = out1 + (size_t)MEM_SIZE * DIM;         // +128e6

    fused_kernel<<<TOTAL_BLOCKS, 256, 0, stream>>>(
        video, audio, y, neg, v1, v2,
        scores, (fx4*)out1, (fx4*)out2);

    scatter_kernel<<<2 * BS, 64, 0, stream>>>(video, audio, y, v1, v2,
                                              out1, out2);
}

// Round 4
// 406.549 us; speedup vs baseline: 1.4270x; 1.0531x over previous
//
#include <hip/hip_runtime.h>

#define MEM_SIZE 1000000
#define DIM 128
#define BS 256
#define K 1024
#define NSC (K + 1)   // 1025 scores per (modality, batch)

constexpr float INV_TEMP = 1.0f / 0.07f;
constexpr float MOM = 0.5f;

#define NB 2048                      // blocks
#define BT 128                       // threads per block (2 waves)
#define STRIDE ((long long)NB * BT)  // 262144 fx4 per iteration
#define MARGIN_ROWS 24576            // trail the copy frontier by ~3 iters

typedef float fx4 __attribute__((ext_vector_type(4)));

__device__ __forceinline__ float wave_reduce_sum(float v) {
    #pragma unroll
    for (int off = 32; off > 0; off >>= 1)
        v += __shfl_xor(v, off, 64);
    return v;
}

// Processes all not-yet-done entries whose row < rmax. key = (row<<11)|j.
// Wave-cooperative: each ready entry's 512B row is gathered by all 64 lanes
// (float2 per lane), reduced, and lane==src writes the score.
__device__ __forceinline__ void drain(unsigned key, bool& done, int rmax,
                                      const float2* __restrict__ gmem,
                                      float qx, float qy,
                                      float* __restrict__ srow, int lane) {
    const bool rdy = !done && (int)(key >> 11) < rmax;
    unsigned long long msk = __ballot(rdy);
    while (msk) {
        const int src = __ffsll((long long)msk) - 1;
        msk &= msk - 1;
        const unsigned k = (unsigned)__shfl((int)key, src, 64);
        const int row = (int)(k >> 11);
        const int j = (int)(k & 2047u);
        const float2 x = gmem[(size_t)row * 64 + lane];
        const float sc = wave_reduce_sum(x.x * qx + x.y * qy);
        if (lane == src) srow[j] = sc * INV_TEMP;
    }
    done = done || rdy;
}

// Homogeneous fused kernel: every block copies its stride-slice of both banks
// AND owns one slice of scores for one (m,b) unit, draining score gathers just
// behind its own copy frontier so gathers hit L3 (copy just streamed the rows).
__global__ __launch_bounds__(BT, 4) void fused_kernel(
    const float* __restrict__ video, const float* __restrict__ audio,
    const int* __restrict__ y, const int* __restrict__ neg,
    const float* __restrict__ view1, const float* __restrict__ view2,
    float* __restrict__ scores,
    fx4* __restrict__ out1, fx4* __restrict__ out2) {
    const int bid = blockIdx.x;
    const int tid = threadIdx.x;
    const int lane = tid & 63;
    const int wv = tid >> 6;            // wave 0..1
    const int u = bid >> 2;             // score unit 0..511
    const int s = bid & 3;              // slice 0..3
    const int m = u >> 8;               // 0: view2·v, 1: view1·a
    const int b = u & (BS - 1);
    const int yb = y[b];

    // block-uniform normalized query (held in 2 VGPRs)
    const float* emb = (m == 0) ? video : audio;
    const float2 e = reinterpret_cast<const float2*>(emb + b * DIM)[lane];
    const float ss = wave_reduce_sum(e.x * e.x + e.y * e.y);
    const float qinv = 1.0f / fmaxf(sqrtf(ss), 1e-12f);
    const float qx = e.x * qinv, qy = e.y * qinv;

    // this wave's 128 negative-score entries: j = jbase + {lane, lane+64}
    const int jbase = 1 + s * 256 + wv * 128;
    const int j0 = jbase + lane;
    const int j1 = jbase + 64 + lane;
    const int ni0 = neg[b * K + j0 - 1];
    const int ni1 = neg[b * K + j1 - 1];
    const int r0 = ni0 + (ni0 >= yb ? 1 : 0);
    const int r1 = ni1 + (ni1 >= yb ? 1 : 0);
    const unsigned key0 = ((unsigned)r0 << 11) | (unsigned)j0;
    const unsigned key1 = ((unsigned)r1 << 11) | (unsigned)j1;
    bool done0 = false, done1 = false;

    const float2* gmem =
        reinterpret_cast<const float2*>((m == 0) ? view2 : view1);
    float* srow = scores + (size_t)u * NSC;

    const fx4* s1 = reinterpret_cast<const fx4*>(view1);
    const fx4* s2 = reinterpret_cast<const fx4*>(view2);

    const long long n4 = (long long)MEM_SIZE * DIM / 4;   // 32,000,000 fx4
    long long i = (long long)bid * BT + tid;
    long long ibase = (long long)bid * BT;                // block frontier proxy
    for (; i < n4; i += STRIDE, ibase += STRIDE) {
        // copy (normal loads -> populate L3; nt stores -> don't pollute)
        const fx4 a = s1[i];
        const fx4 c = s2[i];
        __builtin_nontemporal_store(a, &out1[i]);
        __builtin_nontemporal_store(c, &out2[i]);
        // drain score entries well behind the frontier (L3-resident rows)
        const int rmax = (int)(ibase >> 5) - MARGIN_ROWS;
        drain(key0, done0, rmax, gmem, qx, qy, srow, lane);
        drain(key1, done1, rmax, gmem, qx, qy, srow, lane);
    }
    // final drain: everything left (rows near the end, just streamed)
    drain(key0, done0, 0x7fffffff, gmem, qx, qy, srow, lane);
    drain(key1, done1, 0x7fffffff, gmem, qx, qy, srow, lane);

    // positive score (j=0): one wave per unit
    if (s == 0 && wv == 0) {
        const float2 x = gmem[(size_t)yb * 64 + lane];
        const float sc = wave_reduce_sum(x.x * qx + x.y * qy);
        if (lane == 0) srow[0] = sc * INV_TEMP;
    }
}

// Overwrite the 256 momentum-updated rows per bank (after the copy).
// Duplicate y: numpy "last wins" -> skip b if a later b' has the same index.
__global__ void scatter_kernel(const float* __restrict__ video,
                               const float* __restrict__ audio,
                               const int* __restrict__ y,
                               const float* __restrict__ view1,
                               const float* __restrict__ view2,
                               float* __restrict__ out1,
                               float* __restrict__ out2) {
    const int blk = blockIdx.x;
    const int lane = threadIdx.x;
    const int bank = blk >> 8;
    const int b = blk & (BS - 1);
    const int row = y[b];
    for (int b2 = b + 1; b2 < BS; ++b2)
        if (y[b2] == row) return;   // a later write supersedes this one

    const float* emb = (bank == 0) ? video : audio;
    const float2 e = reinterpret_cast<const float2*>(emb + b * DIM)[lane];
    const float ss = wave_reduce_sum(e.x * e.x + e.y * e.y);
    const float inv = 1.0f / fmaxf(sqrtf(ss), 1e-12f);
    const float vx = e.x * inv, vy = e.y * inv;

    const float* mem = (bank == 0) ? view1 : view2;
    const float2 xp =
        reinterpret_cast<const float2*>(mem + (size_t)row * DIM)[lane];
    float2 nv = make_float2(MOM * xp.x + (1.0f - MOM) * vx,
                            MOM * xp.y + (1.0f - MOM) * vy);
    const float ss2 = wave_reduce_sum(nv.x * nv.x + nv.y * nv.y);
    const float inv2 = 1.0f / fmaxf(sqrtf(ss2), 1e-12f);
    float* out = (bank == 0) ? out1 : out2;
    reinterpret_cast<float2*>(out + (size_t)row * DIM)[lane] =
        make_float2(nv.x * inv2, nv.y * inv2);
}

extern "C" void kernel_launch(void* const* d_in, const int* in_sizes, int n_in,
                              void* d_out, int out_size, void* d_ws, size_t ws_size,
                              hipStream_t stream) {
    const float* video = (const float*)d_in[0];
    const float* audio = (const float*)d_in[1];
    const int* y       = (const int*)d_in[2];
    const int* neg     = (const int*)d_in[3];
    const float* v1    = (const float*)d_in[4];
    const float* v2    = (const float*)d_in[5];

    float* out    = (float*)d_out;
    float* scores = out;                                   // [2,256,1025]
    float* out1   = out + 2 * BS * NSC;                    // +524800 (16B-aligned)
    float* out2   = out1 + (size_t)MEM_SIZE * DIM;

    fused_kernel<<<NB, BT, 0, stream>>>(
        video, audio, y, neg, v1, v2,
        scores, (fx4*)out1, (fx4*)out2);

    scatter_kernel<<<2 * BS, 64, 0, stream>>>(video, audio, y, v1, v2,
                                              out1, out2);
}